// Round 4
// baseline (56.320 us; speedup 1.0000x reference)
//
#include <hip/hip_runtime.h>
#include <hip/hip_bf16.h>

#define DDIM 4096
#define ADIM 21
#define BM   64                 // rows per block
#define KC   128                // k per chunk
#define NCHH 16                 // chunks per K-half (D/KC/2)
#define NTHR 256                // 4 waves

typedef __attribute__((ext_vector_type(8))) short bf16x8;
typedef __attribute__((ext_vector_type(4))) float f32x4;

// LDS: x tile [64][128] bf16 (16KB) x2, W tile [32][128] bf16 (8KB) x2 = 48KB
#define XOFF(b) ((b) * 16384)
#define WOFF(b) (32768 + (b) * 8192)

// row-major [row][k] bf16, row stride 256B; XOR-swizzle 16B granules so that
// 16 consecutive rows at the same k map to 8 distinct bank-groups (2-way=free)
__device__ __forceinline__ int swz(int row, int kbyte) {
    return (row * 256 + kbyte) ^ ((row & 7) << 4);
}

__device__ __forceinline__ unsigned pk2(float lo, float hi) {
    unsigned short a = __builtin_bit_cast(unsigned short, __float2bfloat16(lo));
    unsigned short b = __builtin_bit_cast(unsigned short, __float2bfloat16(hi));
    return (unsigned)a | ((unsigned)b << 16);
}

// K split in 2 across blockIdx.y -> 512 blocks (2/CU, 2 waves/SIMD) and the
// serial chunk chain halves. The two partial contributions per output are
// combined with fp32 atomicAdd (2 commutative adds -> order-independent value).
__global__ __launch_bounds__(NTHR, 2)
void fem_mfma(const float* __restrict__ x,
              const float* __restrict__ v,
              const float* __restrict__ W,
              const float* __restrict__ bias,
              float* __restrict__ result,   // [B], pre-zeroed
              float* __restrict__ out)      // [B][ADIM], pre-zeroed
{
    __shared__ char smem[49152];
    const int t = threadIdx.x;
    const int rowbase = blockIdx.x * BM;
    const int cb = blockIdx.y * NCHH;      // chunk base for this K-half

    float4 xA[8], xB[8], wA[4], wB[4];

    auto issue = [&](int c, float4 xr[8], float4 wr[4]) {
        const float* xs = x + (size_t)(rowbase + (t >> 4)) * DDIM + c * KC + (t & 15) * 8;
#pragma unroll
        for (int j = 0; j < 4; ++j) {
            const float* s = xs + (size_t)j * 16 * DDIM;
            xr[2 * j]     = *(const float4*)s;
            xr[2 * j + 1] = *(const float4*)(s + 4);
        }
        const float* ws = W + (size_t)(t >> 4) * DDIM + c * KC + (t & 15) * 8;
        wr[0] = *(const float4*)ws;
        wr[1] = *(const float4*)(ws + 4);
        if (t < 80) {                       // W rows 16..20
            const float* w2 = W + (size_t)(16 + (t >> 4)) * DDIM + c * KC + (t & 15) * 8;
            wr[2] = *(const float4*)w2;
            wr[3] = *(const float4*)(w2 + 4);
        }
    };

    auto write_stage = [&](int buf, const float4 xr[8], const float4 wr[4]) {
        char* xb = smem + XOFF(buf);
        const int kg = t & 15;
#pragma unroll
        for (int j = 0; j < 4; ++j) {
            const int row = (t >> 4) + j * 16;
            uint4 g;
            g.x = pk2(xr[2 * j].x, xr[2 * j].y);
            g.y = pk2(xr[2 * j].z, xr[2 * j].w);
            g.z = pk2(xr[2 * j + 1].x, xr[2 * j + 1].y);
            g.w = pk2(xr[2 * j + 1].z, xr[2 * j + 1].w);
            *(uint4*)(xb + swz(row, kg * 16)) = g;
        }
        char* wb = smem + WOFF(buf);
        {
            uint4 g;
            g.x = pk2(wr[0].x, wr[0].y); g.y = pk2(wr[0].z, wr[0].w);
            g.z = pk2(wr[1].x, wr[1].y); g.w = pk2(wr[1].z, wr[1].w);
            *(uint4*)(wb + swz(t >> 4, kg * 16)) = g;
        }
        if (t < 80) {
            uint4 g;
            g.x = pk2(wr[2].x, wr[2].y); g.y = pk2(wr[2].z, wr[2].w);
            g.z = pk2(wr[3].x, wr[3].y); g.w = pk2(wr[3].z, wr[3].w);
            *(uint4*)(wb + swz(16 + (t >> 4), kg * 16)) = g;
        }
    };

    const int lane = t & 63;
    const int wv   = t >> 6;            // wave id 0..3, owns 16 rows
    const int a0   = lane & 15;         // annotator col
    const int kh   = (lane >> 4) * 8;   // k sub-offset within K=32

    f32x4 acc0, acc1;
    if (blockIdx.y == 0) {              // bias contributed by K-half 0 only
        const float ba0 = bias[a0];
        const float ba1 = (a0 < 5) ? bias[16 + a0] : 0.f;
        acc0 = (f32x4){ba0, ba0, ba0, ba0};
        acc1 = (f32x4){ba1, ba1, ba1, ba1};
    } else {
        acc0 = (f32x4){0.f, 0.f, 0.f, 0.f};
        acc1 = (f32x4){0.f, 0.f, 0.f, 0.f};
    }

    auto compute = [&](int buf) {
        const char* xb = smem + XOFF(buf);
        const char* wb = smem + WOFF(buf);
        const int rowA = wv * 16 + (lane & 15);
#pragma unroll
        for (int k0 = 0; k0 < KC; k0 += 32) {
            bf16x8 a  = *(const bf16x8*)(xb + swz(rowA,    (k0 + kh) * 2));
            bf16x8 b0 = *(const bf16x8*)(wb + swz(a0,      (k0 + kh) * 2));
            bf16x8 b1 = *(const bf16x8*)(wb + swz(16 + a0, (k0 + kh) * 2));
            acc0 = __builtin_amdgcn_mfma_f32_16x16x32_bf16(a, b0, acc0, 0, 0, 0);
            acc1 = __builtin_amdgcn_mfma_f32_16x16x32_bf16(a, b1, acc1, 0, 0, 0);
        }
    };

    // prologue: zero W rows 21..31 (both buffers), prime 2-deep pipeline
    if (t < 176) {
        const int row = 21 + (t >> 4), kg = t & 15;
        const uint4 z = {0, 0, 0, 0};
        *(uint4*)(smem + WOFF(0) + swz(row, kg * 16)) = z;
        *(uint4*)(smem + WOFF(1) + swz(row, kg * 16)) = z;
    }
    issue(cb + 0, xA, wA);
    write_stage(0, xA, wA);
    issue(cb + 1, xB, wB);
    __syncthreads();

    for (int c = 0; c < NCHH; c += 2) {
        if (c + 2 < NCHH) issue(cb + c + 2, xA, wA);
        compute(0);
        __syncthreads();
        write_stage(1, xB, wB);
        if (c + 3 < NCHH) issue(cb + c + 3, xB, wB);
        __syncthreads();
        compute(1);
        __syncthreads();
        if (c + 2 < NCHH) write_stage(0, xA, wA);
        __syncthreads();
    }

    // epilogue: D layout row=(lane>>4)*4+reg, col=lane&15; atomic-combine the
    // two K-half contributions (exactly 2 adds/element, commutative -> exact)
    const size_t growbase = (size_t)rowbase + wv * 16 + (lane >> 4) * 4;
#pragma unroll
    for (int r = 0; r < 4; ++r) {
        const size_t row = growbase + r;
        float o0 = acc0[r];
        atomicAdd(&out[row * ADIM + a0], o0);
        float p = o0 * v[row * ADIM + a0];
        if (a0 < 5) {
            float o1 = acc1[r];
            atomicAdd(&out[row * ADIM + 16 + a0], o1);
            p += o1 * v[row * ADIM + 16 + a0];
        }
        p += __shfl_xor(p, 1);
        p += __shfl_xor(p, 2);
        p += __shfl_xor(p, 4);
        p += __shfl_xor(p, 8);
        if (a0 == 0) atomicAdd(&result[row], p);
    }
}

extern "C" void kernel_launch(void* const* d_in, const int* in_sizes, int n_in,
                              void* d_out, int out_size, void* d_ws, size_t ws_size,
                              hipStream_t stream) {
    const float* x  = (const float*)d_in[0];
    const float* v  = (const float*)d_in[1];
    const float* W  = (const float*)d_in[2];
    const float* b  = (const float*)d_in[3];

    const int B = in_sizes[0] / DDIM;     // 16384

    float* result = (float*)d_out;        // [B]
    float* out    = (float*)d_out + B;    // [B][ADIM]

    // accumulate with atomics -> zero the outputs every launch (capture-safe)
    hipMemsetAsync(d_out, 0, (size_t)out_size * sizeof(float), stream);

    fem_mfma<<<dim3(B / BM, 2), dim3(NTHR), 0, stream>>>(x, v, W, b, result, out);
}